// Round 2
// baseline (5251.915 us; speedup 1.0000x reference)
//
#include <hip/hip_runtime.h>
#include <hip/hip_bf16.h>
#include <math.h>

// Problem constants
#define BB     256
#define NMEL   80
#define TMEL   800
#define NFR    16          // frames per step
#define TT     50          // decoder steps
#define RNN    1024
#define ENC    256
#define INDIM  1280        // RNN + ENC == MEL_DIM
#define G4     4096        // 4*RNN
#define MROWS  (TT*BB)     // 12800

typedef __attribute__((ext_vector_type(8))) short bf16x8;
typedef __attribute__((ext_vector_type(4))) float f32x4;

#define GAS __attribute__((address_space(1)))
#define LAS __attribute__((address_space(3)))

__device__ __forceinline__ unsigned short f2bf(float f) {
    unsigned int u = __float_as_uint(f);
    u += 0x7FFFu + ((u >> 16) & 1u);     // round-to-nearest-even
    return (unsigned short)(u >> 16);
}
__device__ __forceinline__ float bf2f(unsigned short s) {
    return __uint_as_float(((unsigned int)s) << 16);
}

// ---------------- prep kernels ----------------

__global__ void k_f32_to_bf16(const float* __restrict__ src,
                              unsigned short* __restrict__ dst, int n) {
    for (int i = blockIdx.x * blockDim.x + threadIdx.x; i < n;
         i += gridDim.x * blockDim.x)
        dst[i] = f2bf(src[i]);
}

// W_proj[:, 0:1024] -> bf16 [1280][1024]
__global__ void k_conv_wph(const float* __restrict__ wproj,
                           unsigned short* __restrict__ dst) {
    const int n = INDIM * RNN;
    for (int i = blockIdx.x * blockDim.x + threadIdx.x; i < n;
         i += gridDim.x * blockDim.x) {
        int m = i >> 10, k = i & 1023;
        dst[i] = f2bf(wproj[m * INDIM + k]);
    }
}

// teacher-forced inputs: frames[t][b][k] = (t==0)?0:target[b][k%80][t*16+k/80]
__global__ void k_frames(const float* __restrict__ target,
                         unsigned short* __restrict__ frames) {
    const int n = TT * BB * INDIM;
    for (int i = blockIdx.x * blockDim.x + threadIdx.x; i < n;
         i += gridDim.x * blockDim.x) {
        int k = i % INDIM;
        int rb = i / INDIM;
        int b = rb & (BB - 1);
        int t = rb >> 8;
        unsigned short v = 0;
        if (t > 0) {
            int mel = k % NMEL, fr = k / NMEL;
            v = f2bf(target[(b * NMEL + mel) * TMEL + t * NFR + fr]);
        }
        frames[i] = v;
    }
}

// ctxproj[b][m] = b_proj[m] + context[b]·W_proj[m][1024:1280]
__global__ void k_ctxproj(const float* __restrict__ context,
                          const float* __restrict__ wproj,
                          const float* __restrict__ bproj,
                          float* __restrict__ ctx) {
    int i = blockIdx.x * blockDim.x + threadIdx.x;
    if (i >= BB * INDIM) return;
    int m = i % INDIM, b = i / INDIM;
    const float* wr = wproj + m * INDIM + RNN;
    const float* cb = context + b * ENC;
    float acc = bproj[m];
    for (int e = 0; e < ENC; ++e) acc += cb[e] * wr[e];
    ctx[i] = acc;
}

// gatectx[b] = b_gate + context[b]·W_gate[0][1024:1280]
__global__ void k_gatectx(const float* __restrict__ context,
                          const float* __restrict__ wgate,
                          const float* __restrict__ bgate,
                          float* __restrict__ gctx) {
    int b = blockIdx.x * blockDim.x + threadIdx.x;
    if (b >= BB) return;
    float acc = bgate[0];
    const float* cb = context + b * ENC;
    for (int e = 0; e < ENC; ++e) acc += cb[e] * wgate[RNN + e];
    gctx[b] = acc;
}

// ---------------- m97-structure tile GEMM core ----------------
// 128x128 WG tile, BK=32, 4 waves of 64x64, global_load_lds(16B) staging,
// 2-barrier K loop. A [M][STRIDE], Bw [N][STRIDE] (row-major, C = A@Bw^T).
template<int STRIDE, int KDIM>
__device__ __forceinline__ void gemm_core(const unsigned short* __restrict__ A,
                                          const unsigned short* __restrict__ Bw,
                                          int mblk, int nblk,
                                          unsigned short* As, unsigned short* Bs,
                                          f32x4 acc[4][4]) {
    const int tid = threadIdx.x, lane = tid & 63, wid = tid >> 6;
    const int wm = (wid >> 1) * 64, wn = (wid & 1) * 64;
    const int lr = lane & 15, lko = (lane >> 4) * 8;
    // staging: chunk c covers LDS bytes [c*16, c*16+16); lane l of a call with
    // uniform base chunk cb gets chunk cb+l (HW adds lane*16 to LDS dest).
    const int c0 = wid * 128 + lane;          // call 0 chunk for this lane
    const int c1 = c0 + 64;                   // call 1
    const int r0 = c0 >> 2, o0 = (c0 & 3) * 8;
    const int r1 = c1 >> 2, o1 = (c1 & 3) * 8;
    const unsigned short* a0p = A + (size_t)(mblk + r0) * STRIDE + o0;
    const unsigned short* a1p = A + (size_t)(mblk + r1) * STRIDE + o1;
    const unsigned short* b0p = Bw + (size_t)(nblk + r0) * STRIDE + o0;
    const unsigned short* b1p = Bw + (size_t)(nblk + r1) * STRIDE + o1;
    unsigned short* da0 = As + wid * 1024;          // uniform per wave
    unsigned short* da1 = As + wid * 1024 + 512;
    unsigned short* db0 = Bs + wid * 1024;
    unsigned short* db1 = Bs + wid * 1024 + 512;
    for (int k0 = 0; k0 < KDIM; k0 += 32) {
        __syncthreads();   // previous compute done before LDS overwrite
        __builtin_amdgcn_global_load_lds((const GAS unsigned int*)(a0p + k0),
                                         (LAS unsigned int*)da0, 16, 0, 0);
        __builtin_amdgcn_global_load_lds((const GAS unsigned int*)(a1p + k0),
                                         (LAS unsigned int*)da1, 16, 0, 0);
        __builtin_amdgcn_global_load_lds((const GAS unsigned int*)(b0p + k0),
                                         (LAS unsigned int*)db0, 16, 0, 0);
        __builtin_amdgcn_global_load_lds((const GAS unsigned int*)(b1p + k0),
                                         (LAS unsigned int*)db1, 16, 0, 0);
        __syncthreads();   // compiler drains vmcnt before barrier
        bf16x8 af[4], bfv[4];
        #pragma unroll
        for (int mi = 0; mi < 4; ++mi)
            af[mi] = *(const bf16x8*)(As + (wm + mi * 16 + lr) * 32 + lko);
        #pragma unroll
        for (int ni = 0; ni < 4; ++ni)
            bfv[ni] = *(const bf16x8*)(Bs + (wn + ni * 16 + lr) * 32 + lko);
        #pragma unroll
        for (int mi = 0; mi < 4; ++mi)
            #pragma unroll
            for (int ni = 0; ni < 4; ++ni)
                acc[mi][ni] = __builtin_amdgcn_mfma_f32_16x16x32_bf16(
                    af[mi], bfv[ni], acc[mi][ni], 0, 0, 0);
    }
}

// GEMM 1: xproj = frames @ W_ih^T + b_ih + b_hh (bf16 out). M=12800 N=4096 K=1280
__global__ __launch_bounds__(256) void k_gemm_xproj(
    const unsigned short* __restrict__ A,   // [12800][1280]
    const unsigned short* __restrict__ Bw,  // [4096][1280]
    const float* __restrict__ b_ih, const float* __restrict__ b_hh,
    unsigned short* __restrict__ Cout)      // [12800][4096]
{
    __shared__ unsigned short As[4096], Bs[4096];
    f32x4 acc[4][4] = {};
    const int mblk = blockIdx.y * 128, nblk = blockIdx.x * 128;
    gemm_core<INDIM, INDIM>(A, Bw, mblk, nblk, As, Bs, acc);
    const int lane = threadIdx.x & 63, wid = threadIdx.x >> 6;
    const int wm = (wid >> 1) * 64, wn = (wid & 1) * 64, lr = lane & 15;
    #pragma unroll
    for (int ni = 0; ni < 4; ++ni) {
        const int col = nblk + wn + ni * 16 + lr;
        const float bias = b_ih[col] + b_hh[col];
        #pragma unroll
        for (int mi = 0; mi < 4; ++mi) {
            const int row0 = mblk + wm + mi * 16 + (lane >> 4) * 4;
            #pragma unroll
            for (int r = 0; r < 4; ++r)
                Cout[(size_t)(row0 + r) * G4 + col] = f2bf(acc[mi][ni][r] + bias);
        }
    }
}

// GEMM 2: mel = h_all[1:] @ Wp_h^T + ctxproj, scatter to output. M=12800 N=1280 K=1024
__global__ __launch_bounds__(256) void k_gemm_mel(
    const unsigned short* __restrict__ A,   // [12800][1024]
    const unsigned short* __restrict__ Bw,  // [1280][1024]
    const float* __restrict__ ctxproj,      // [256][1280]
    float* __restrict__ out0)               // [256][80][800]
{
    __shared__ unsigned short As[4096], Bs[4096];
    f32x4 acc[4][4] = {};
    const int mblk = blockIdx.y * 128, nblk = blockIdx.x * 128;
    gemm_core<RNN, RNN>(A, Bw, mblk, nblk, As, Bs, acc);
    const int lane = threadIdx.x & 63, wid = threadIdx.x >> 6;
    const int wm = (wid >> 1) * 64, wn = (wid & 1) * 64, lr = lane & 15;
    #pragma unroll
    for (int ni = 0; ni < 4; ++ni) {
        const int col = nblk + wn + ni * 16 + lr;     // [0,1280)
        const int mel = col % NMEL, fr = col / NMEL;
        #pragma unroll
        for (int mi = 0; mi < 4; ++mi) {
            const int row0 = mblk + wm + mi * 16 + (lane >> 4) * 4;
            #pragma unroll
            for (int r = 0; r < 4; ++r) {
                const int row = row0 + r;             // t*256 + b
                const int t = row >> 8, b = row & 255;
                out0[(size_t)(b * NMEL + mel) * TMEL + t * NFR + fr] =
                    acc[mi][ni][r] + ctxproj[b * INDIM + col];
            }
        }
    }
}

// ---------------- persistent recurrence kernel ----------------
// Grid: 256 WGs x 512 threads. WG (mb = bid&7, nb = bid>>3) owns the
// 32x32 output tile b in [mb*32,+32), j in [nb*32,+32) for ALL 4 gates,
// for all 50 steps. Whh slice lives in registers (128 VGPR/lane).
// Wave wv: ns = wv&1 (16-col half), kh = wv>>1 (256-wide K quarter).
// Step t+1 of group mb only needs h rows [mb*32,+32) -> 32-WG barrier
// per b-block group via device-scope atomics (not grid-wide).
__global__ __launch_bounds__(512, 2) void k_recurrence(
    const unsigned short* __restrict__ Whh,    // [4096][1024] bf16
    const unsigned short* __restrict__ xproj,  // [50][256][4096] bf16
    unsigned short* __restrict__ h_all,        // [51][256][1024] bf16
    unsigned int* __restrict__ bar)            // [8][64] zeroed per call
{
    __shared__ float gates[4 * 32 * 33];       // +1 pad: conflict-free ds_add
    __shared__ float c_lds[32 * 32];           // cell state, persistent
    const int tid = threadIdx.x, lane = tid & 63, wv = tid >> 6;
    const int ns = wv & 1, kh = wv >> 1;
    const int mb = blockIdx.x & 7, nb = blockIdx.x >> 3;
    const int m0 = mb * 32, n0 = nb * 32;
    const int lr = lane & 15, lk = (lane >> 4) * 8;

    // load this wave's Whh slice into registers: 4 gates x 8 k-tiles
    bf16x8 wf[4][8];
    #pragma unroll
    for (int g = 0; g < 4; ++g)
        #pragma unroll
        for (int kt = 0; kt < 8; ++kt)
            wf[g][kt] = *(const bf16x8*)(Whh +
                (size_t)(g * RNN + n0 + ns * 16 + lr) * RNN +
                kh * 256 + kt * 32 + lk);

    for (int i = tid; i < 1024; i += 512) c_lds[i] = 0.f;

    // xproj staging mapping: thread -> (gate, row, 8-col chunk)
    const int xg = tid >> 7, xlm = (tid >> 2) & 31, xnc = tid & 3;

    for (int t = 0; t < TT; ++t) {
        const unsigned short* xp = xproj + (size_t)t * BB * G4;
        const unsigned short* hp = h_all + (size_t)t * BB * RNN;
        __syncthreads();                       // gates free for reuse
        // phase 0: gates := xproj tile (fused bias/input projection)
        {
            bf16x8 xv = *(const bf16x8*)(xp + (size_t)(m0 + xlm) * G4 +
                                         xg * RNN + n0 + xnc * 8);
            #pragma unroll
            for (int j = 0; j < 8; ++j)
                gates[(xg * 32 + xlm) * 33 + xnc * 8 + j] =
                    bf2f((unsigned short)xv[j]);
        }
        // phase 1: partial h @ Whh^T for this wave's K quarter
        f32x4 acc[4][2] = {};                  // [gate][m-frag]
        const unsigned short* hw = hp + (size_t)(m0 + lr) * RNN + kh * 256 + lk;
        #pragma unroll
        for (int kt = 0; kt < 8; ++kt) {
            bf16x8 a0 = *(const bf16x8*)(hw + kt * 32);
            bf16x8 a1 = *(const bf16x8*)(hw + 16 * RNN + kt * 32);
            #pragma unroll
            for (int g = 0; g < 4; ++g) {
                acc[g][0] = __builtin_amdgcn_mfma_f32_16x16x32_bf16(
                    a0, wf[g][kt], acc[g][0], 0, 0, 0);
                acc[g][1] = __builtin_amdgcn_mfma_f32_16x16x32_bf16(
                    a1, wf[g][kt], acc[g][1], 0, 0, 0);
            }
        }
        __syncthreads();                       // phase-0 stores visible
        // phase 2: reduce K quarters via LDS float atomics
        const int rbase = (lane >> 4) * 4;
        #pragma unroll
        for (int g = 0; g < 4; ++g)
            #pragma unroll
            for (int mi = 0; mi < 2; ++mi)
                #pragma unroll
                for (int r = 0; r < 4; ++r)
                    atomicAdd(&gates[(g * 32 + mi * 16 + rbase + r) * 33 +
                                     ns * 16 + lr], acc[g][mi][r]);
        __syncthreads();
        // phase 3: LSTM elementwise; c stays in LDS; h -> global bf16
        unsigned short* hn = h_all + (size_t)(t + 1) * BB * RNN;
        #pragma unroll
        for (int q = 0; q < 2; ++q) {
            const int e = tid + q * 512;
            const int lm = e >> 5, ln = e & 31;
            const float xi = gates[(0 * 32 + lm) * 33 + ln];
            const float xf = gates[(1 * 32 + lm) * 33 + ln];
            const float xg_ = gates[(2 * 32 + lm) * 33 + ln];
            const float xo = gates[(3 * 32 + lm) * 33 + ln];
            const float si = 1.f / (1.f + expf(-xi));
            const float sf = 1.f / (1.f + expf(-xf));
            const float so = 1.f / (1.f + expf(-xo));
            const float cp = c_lds[lm * 32 + ln];
            const float cn = sf * cp + si * tanhf(xg_);
            const float hnv = so * tanhf(cn);
            c_lds[lm * 32 + ln] = cn;
            hn[(size_t)(m0 + lm) * RNN + n0 + ln] = f2bf(hnv);
        }
        // phase 4: 32-WG b-block-group barrier (skip after last step)
        if (t < TT - 1) {
            __threadfence();                   // release h writes (agent)
            __syncthreads();
            if (tid == 0) {
                __hip_atomic_fetch_add(&bar[mb * 64 + t], 1u,
                                       __ATOMIC_ACQ_REL, __HIP_MEMORY_SCOPE_AGENT);
                unsigned v = 0; int polls = 0;
                do {
                    v = __hip_atomic_load(&bar[mb * 64 + t], __ATOMIC_ACQUIRE,
                                          __HIP_MEMORY_SCOPE_AGENT);
                    if (v >= 32u) break;
                    __builtin_amdgcn_s_sleep(2);
                } while (++polls < (1 << 22));  // bounded: no infinite hang
            }
            __syncthreads();
            __threadfence();                   // acquire: invalidate L1
        }
    }
}

// gate[b*50+t] = gatectx[b] + h_all[t+1][b]·w_gate[0:1024] ; one wave per row
__global__ void k_gate(const unsigned short* __restrict__ h,  // [12800][1024]
                       const float* __restrict__ wgate,
                       const float* __restrict__ gctx,
                       float* __restrict__ out1) {
    const int gw = (blockIdx.x * blockDim.x + threadIdx.x) >> 6;
    const int lane = threadIdx.x & 63;
    if (gw >= MROWS) return;
    const unsigned short* hr = h + (size_t)gw * RNN + lane * 16;
    const float* wr = wgate + lane * 16;
    float acc = 0.f;
    #pragma unroll
    for (int j = 0; j < 16; ++j) acc += bf2f(hr[j]) * wr[j];
    for (int off = 32; off; off >>= 1) acc += __shfl_down(acc, off);
    if (lane == 0) {
        const int t = gw >> 8, b = gw & 255;
        out1[b * TT + t] = acc + gctx[b];
    }
}

// ---------------- workspace layout (all offsets 1KB-aligned) ----------------
static const size_t OFF_WIH   = 0;                                    // 10.5 MB
static const size_t OFF_WHH   = OFF_WIH   + (size_t)G4 * INDIM * 2;   // 8 MB
static const size_t OFF_WPH   = OFF_WHH   + (size_t)G4 * RNN * 2;     // 2.6 MB
static const size_t OFF_FRM   = OFF_WPH   + (size_t)INDIM * RNN * 2;  // 32.8 MB
static const size_t OFF_XPROJ = OFF_FRM   + (size_t)MROWS * INDIM * 2;// 104.9 MB
static const size_t OFF_HALL  = OFF_XPROJ + (size_t)MROWS * G4 * 2;   // 26.7 MB
static const size_t OFF_CTX   = OFF_HALL  + (size_t)(TT + 1) * BB * RNN * 2;
static const size_t OFF_GCTX  = OFF_CTX   + (size_t)BB * INDIM * 4;
static const size_t OFF_BAR   = OFF_GCTX  + 1024;

extern "C" void kernel_launch(void* const* d_in, const int* in_sizes, int n_in,
                              void* d_out, int out_size, void* d_ws, size_t ws_size,
                              hipStream_t stream) {
    const float* context = (const float*)d_in[0];
    const float* target  = (const float*)d_in[1];
    const float* W_ih    = (const float*)d_in[2];
    const float* b_ih    = (const float*)d_in[3];
    const float* W_hh    = (const float*)d_in[4];
    const float* b_hh    = (const float*)d_in[5];
    const float* W_proj  = (const float*)d_in[6];
    const float* b_proj  = (const float*)d_in[7];
    const float* W_gate  = (const float*)d_in[8];
    const float* b_gate  = (const float*)d_in[9];
    float* out = (float*)d_out;
    char* ws = (char*)d_ws;

    unsigned short* wih_bf  = (unsigned short*)(ws + OFF_WIH);
    unsigned short* whh_bf  = (unsigned short*)(ws + OFF_WHH);
    unsigned short* wph_bf  = (unsigned short*)(ws + OFF_WPH);
    unsigned short* frames  = (unsigned short*)(ws + OFF_FRM);
    unsigned short* xproj   = (unsigned short*)(ws + OFF_XPROJ);
    unsigned short* h_all   = (unsigned short*)(ws + OFF_HALL);
    float*          ctxproj = (float*)(ws + OFF_CTX);
    float*          gctx    = (float*)(ws + OFF_GCTX);
    unsigned int*   bar     = (unsigned int*)(ws + OFF_BAR);

    // per-call init (harness does not re-zero ws between replays)
    hipMemsetAsync(h_all, 0, (size_t)BB * RNN * 2, stream);   // h0 slot
    hipMemsetAsync(bar, 0, 8 * 64 * 4, stream);               // barrier counters

    k_f32_to_bf16<<<2048, 256, 0, stream>>>(W_ih, wih_bf, G4 * INDIM);
    k_f32_to_bf16<<<2048, 256, 0, stream>>>(W_hh, whh_bf, G4 * RNN);
    k_conv_wph<<<2048, 256, 0, stream>>>(W_proj, wph_bf);
    k_frames<<<2048, 256, 0, stream>>>(target, frames);
    k_ctxproj<<<(BB * INDIM + 255) / 256, 256, 0, stream>>>(context, W_proj,
                                                            b_proj, ctxproj);
    k_gatectx<<<1, 256, 0, stream>>>(context, W_gate, b_gate, gctx);

    k_gemm_xproj<<<dim3(G4 / 128, MROWS / 128), 256, 0, stream>>>(
        frames, wih_bf, b_ih, b_hh, xproj);

    k_recurrence<<<256, 512, 0, stream>>>(whh_bf, xproj, h_all, bar);

    k_gemm_mel<<<dim3(INDIM / 128, MROWS / 128), 256, 0, stream>>>(
        h_all + (size_t)BB * RNN, wph_bf, ctxproj, out);
    k_gate<<<MROWS / 4, 256, 0, stream>>>(h_all + (size_t)BB * RNN, W_gate,
                                          gctx, out + (size_t)BB * NMEL * TMEL);
}

// Round 3
// 2313.510 us; speedup vs baseline: 2.2701x; 2.2701x over previous
//
#include <hip/hip_runtime.h>
#include <hip/hip_bf16.h>
#include <math.h>

// Problem constants
#define BB     256
#define NMEL   80
#define TMEL   800
#define NFR    16          // frames per step
#define TT     50          // decoder steps
#define RNN    1024
#define ENC    256
#define INDIM  1280        // RNN + ENC == MEL_DIM
#define G4     4096        // 4*RNN
#define MROWS  (TT*BB)     // 12800

typedef __attribute__((ext_vector_type(8))) short bf16x8;
typedef __attribute__((ext_vector_type(4))) float f32x4;

#define GAS __attribute__((address_space(1)))
#define LAS __attribute__((address_space(3)))

__device__ __forceinline__ unsigned short f2bf(float f) {
    unsigned int u = __float_as_uint(f);
    u += 0x7FFFu + ((u >> 16) & 1u);     // round-to-nearest-even
    return (unsigned short)(u >> 16);
}
__device__ __forceinline__ float bf2f(unsigned short s) {
    return __uint_as_float(((unsigned int)s) << 16);
}

// ---------------- prep kernels ----------------

__global__ void k_f32_to_bf16(const float* __restrict__ src,
                              unsigned short* __restrict__ dst, int n) {
    for (int i = blockIdx.x * blockDim.x + threadIdx.x; i < n;
         i += gridDim.x * blockDim.x)
        dst[i] = f2bf(src[i]);
}

// W_proj[:, 0:1024] -> bf16 [1280][1024]
__global__ void k_conv_wph(const float* __restrict__ wproj,
                           unsigned short* __restrict__ dst) {
    const int n = INDIM * RNN;
    for (int i = blockIdx.x * blockDim.x + threadIdx.x; i < n;
         i += gridDim.x * blockDim.x) {
        int m = i >> 10, k = i & 1023;
        dst[i] = f2bf(wproj[m * INDIM + k]);
    }
}

// teacher-forced inputs: frames[t][b][k] = (t==0)?0:target[b][k%80][t*16+k/80]
__global__ void k_frames(const float* __restrict__ target,
                         unsigned short* __restrict__ frames) {
    const int n = TT * BB * INDIM;
    for (int i = blockIdx.x * blockDim.x + threadIdx.x; i < n;
         i += gridDim.x * blockDim.x) {
        int k = i % INDIM;
        int rb = i / INDIM;
        int b = rb & (BB - 1);
        int t = rb >> 8;
        unsigned short v = 0;
        if (t > 0) {
            int mel = k % NMEL, fr = k / NMEL;
            v = f2bf(target[(b * NMEL + mel) * TMEL + t * NFR + fr]);
        }
        frames[i] = v;
    }
}

// ctxproj[b][m] = b_proj[m] + context[b]·W_proj[m][1024:1280]
__global__ void k_ctxproj(const float* __restrict__ context,
                          const float* __restrict__ wproj,
                          const float* __restrict__ bproj,
                          float* __restrict__ ctx) {
    int i = blockIdx.x * blockDim.x + threadIdx.x;
    if (i >= BB * INDIM) return;
    int m = i % INDIM, b = i / INDIM;
    const float* wr = wproj + m * INDIM + RNN;
    const float* cb = context + b * ENC;
    float acc = bproj[m];
    for (int e = 0; e < ENC; ++e) acc += cb[e] * wr[e];
    ctx[i] = acc;
}

// gatectx[b] = b_gate + context[b]·W_gate[0][1024:1280]
__global__ void k_gatectx(const float* __restrict__ context,
                          const float* __restrict__ wgate,
                          const float* __restrict__ bgate,
                          float* __restrict__ gctx) {
    int b = blockIdx.x * blockDim.x + threadIdx.x;
    if (b >= BB) return;
    float acc = bgate[0];
    const float* cb = context + b * ENC;
    for (int e = 0; e < ENC; ++e) acc += cb[e] * wgate[RNN + e];
    gctx[b] = acc;
}

// ---------------- m97-structure tile GEMM core ----------------
// 128x128 WG tile, BK=32, 4 waves of 64x64, global_load_lds(16B) staging,
// 2-barrier K loop. A [M][STRIDE], Bw [N][STRIDE] (row-major, C = A@Bw^T).
template<int STRIDE, int KDIM>
__device__ __forceinline__ void gemm_core(const unsigned short* __restrict__ A,
                                          const unsigned short* __restrict__ Bw,
                                          int mblk, int nblk,
                                          unsigned short* As, unsigned short* Bs,
                                          f32x4 acc[4][4]) {
    const int tid = threadIdx.x, lane = tid & 63, wid = tid >> 6;
    const int wm = (wid >> 1) * 64, wn = (wid & 1) * 64;
    const int lr = lane & 15, lko = (lane >> 4) * 8;
    // staging: chunk c covers LDS bytes [c*16, c*16+16); lane l of a call with
    // uniform base chunk cb gets chunk cb+l (HW adds lane*16 to LDS dest).
    const int c0 = wid * 128 + lane;          // call 0 chunk for this lane
    const int c1 = c0 + 64;                   // call 1
    const int r0 = c0 >> 2, o0 = (c0 & 3) * 8;
    const int r1 = c1 >> 2, o1 = (c1 & 3) * 8;
    const unsigned short* a0p = A + (size_t)(mblk + r0) * STRIDE + o0;
    const unsigned short* a1p = A + (size_t)(mblk + r1) * STRIDE + o1;
    const unsigned short* b0p = Bw + (size_t)(nblk + r0) * STRIDE + o0;
    const unsigned short* b1p = Bw + (size_t)(nblk + r1) * STRIDE + o1;
    unsigned short* da0 = As + wid * 1024;          // uniform per wave
    unsigned short* da1 = As + wid * 1024 + 512;
    unsigned short* db0 = Bs + wid * 1024;
    unsigned short* db1 = Bs + wid * 1024 + 512;
    for (int k0 = 0; k0 < KDIM; k0 += 32) {
        __syncthreads();   // previous compute done before LDS overwrite
        __builtin_amdgcn_global_load_lds((const GAS unsigned int*)(a0p + k0),
                                         (LAS unsigned int*)da0, 16, 0, 0);
        __builtin_amdgcn_global_load_lds((const GAS unsigned int*)(a1p + k0),
                                         (LAS unsigned int*)da1, 16, 0, 0);
        __builtin_amdgcn_global_load_lds((const GAS unsigned int*)(b0p + k0),
                                         (LAS unsigned int*)db0, 16, 0, 0);
        __builtin_amdgcn_global_load_lds((const GAS unsigned int*)(b1p + k0),
                                         (LAS unsigned int*)db1, 16, 0, 0);
        __syncthreads();   // compiler drains vmcnt before barrier
        bf16x8 af[4], bfv[4];
        #pragma unroll
        for (int mi = 0; mi < 4; ++mi)
            af[mi] = *(const bf16x8*)(As + (wm + mi * 16 + lr) * 32 + lko);
        #pragma unroll
        for (int ni = 0; ni < 4; ++ni)
            bfv[ni] = *(const bf16x8*)(Bs + (wn + ni * 16 + lr) * 32 + lko);
        #pragma unroll
        for (int mi = 0; mi < 4; ++mi)
            #pragma unroll
            for (int ni = 0; ni < 4; ++ni)
                acc[mi][ni] = __builtin_amdgcn_mfma_f32_16x16x32_bf16(
                    af[mi], bfv[ni], acc[mi][ni], 0, 0, 0);
    }
}

// GEMM 1: xproj = frames @ W_ih^T + b_ih + b_hh (bf16 out). M=12800 N=4096 K=1280
__global__ __launch_bounds__(256) void k_gemm_xproj(
    const unsigned short* __restrict__ A,   // [12800][1280]
    const unsigned short* __restrict__ Bw,  // [4096][1280]
    const float* __restrict__ b_ih, const float* __restrict__ b_hh,
    unsigned short* __restrict__ Cout)      // [12800][4096]
{
    __shared__ unsigned short As[4096], Bs[4096];
    f32x4 acc[4][4] = {};
    const int mblk = blockIdx.y * 128, nblk = blockIdx.x * 128;
    gemm_core<INDIM, INDIM>(A, Bw, mblk, nblk, As, Bs, acc);
    const int lane = threadIdx.x & 63, wid = threadIdx.x >> 6;
    const int wm = (wid >> 1) * 64, wn = (wid & 1) * 64, lr = lane & 15;
    #pragma unroll
    for (int ni = 0; ni < 4; ++ni) {
        const int col = nblk + wn + ni * 16 + lr;
        const float bias = b_ih[col] + b_hh[col];
        #pragma unroll
        for (int mi = 0; mi < 4; ++mi) {
            const int row0 = mblk + wm + mi * 16 + (lane >> 4) * 4;
            #pragma unroll
            for (int r = 0; r < 4; ++r)
                Cout[(size_t)(row0 + r) * G4 + col] = f2bf(acc[mi][ni][r] + bias);
        }
    }
}

// GEMM 2: mel = h_all[1:] @ Wp_h^T + ctxproj, scatter to output. M=12800 N=1280 K=1024
__global__ __launch_bounds__(256) void k_gemm_mel(
    const unsigned short* __restrict__ A,   // [12800][1024]
    const unsigned short* __restrict__ Bw,  // [1280][1024]
    const float* __restrict__ ctxproj,      // [256][1280]
    float* __restrict__ out0)               // [256][80][800]
{
    __shared__ unsigned short As[4096], Bs[4096];
    f32x4 acc[4][4] = {};
    const int mblk = blockIdx.y * 128, nblk = blockIdx.x * 128;
    gemm_core<RNN, RNN>(A, Bw, mblk, nblk, As, Bs, acc);
    const int lane = threadIdx.x & 63, wid = threadIdx.x >> 6;
    const int wm = (wid >> 1) * 64, wn = (wid & 1) * 64, lr = lane & 15;
    #pragma unroll
    for (int ni = 0; ni < 4; ++ni) {
        const int col = nblk + wn + ni * 16 + lr;     // [0,1280)
        const int mel = col % NMEL, fr = col / NMEL;
        #pragma unroll
        for (int mi = 0; mi < 4; ++mi) {
            const int row0 = mblk + wm + mi * 16 + (lane >> 4) * 4;
            #pragma unroll
            for (int r = 0; r < 4; ++r) {
                const int row = row0 + r;             // t*256 + b
                const int t = row >> 8, b = row & 255;
                out0[(size_t)(b * NMEL + mel) * TMEL + t * NFR + fr] =
                    acc[mi][ni][r] + ctxproj[b * INDIM + col];
            }
        }
    }
}

// ---------------- per-step fused LSTM kernel (v2) ----------------
// gates = xproj[t] + h_prev @ Whh^T ; LSTM cell ; h_next(bf16), c(f32 global).
// Grid (32, 8): n0 = bx*32 (cols within RNN), m0 = by*32 (batch rows).
// 512 threads = 8 waves: wave wv -> ns = wv&1 (16-col half), kh = wv>>1
// (256-wide K quarter). Each wave computes partials for ALL 4 gates on its
// (2 m-frags x 1 n-frag) tile; K quarters reduced via LDS float atomics into
// the xproj-initialized gates buffer. 2 waves/SIMD occupancy; Whh slice per
// XCD (bx%8 natural round-robin) = 1MB -> L2-resident across steps.
__global__ __launch_bounds__(512) void k_step(
    const unsigned short* __restrict__ Whh,     // [4096][1024] bf16
    const unsigned short* __restrict__ xproj_t, // [256][4096] bf16
    const unsigned short* __restrict__ h_prev,  // [256][1024] bf16
    unsigned short* __restrict__ h_next,        // [256][1024] bf16
    float* __restrict__ c)                      // [256][1024] f32
{
    __shared__ float gates[4 * 32 * 33];        // +1 pad: conflict-free
    const int tid = threadIdx.x, lane = tid & 63, wv = tid >> 6;
    const int ns = wv & 1, kh = wv >> 1;
    const int n0 = blockIdx.x * 32, m0 = blockIdx.y * 32;
    const int lr = lane & 15, lk = (lane >> 4) * 8;

    // phase 0: gates := xproj tile. thread -> (gate, row, 8-col chunk)
    {
        const int xg = tid >> 7, xlm = (tid >> 2) & 31, xnc = tid & 3;
        bf16x8 xv = *(const bf16x8*)(xproj_t + (size_t)(m0 + xlm) * G4 +
                                     xg * RNN + n0 + xnc * 8);
        #pragma unroll
        for (int j = 0; j < 8; ++j)
            gates[(xg * 32 + xlm) * 33 + xnc * 8 + j] =
                bf2f((unsigned short)xv[j]);
    }

    // phase 1: partial h @ Whh^T for this wave's K quarter (all 4 gates)
    f32x4 acc[4][2] = {};                       // [gate][m-frag]
    const unsigned short* hw = h_prev + (size_t)(m0 + lr) * RNN + kh * 256 + lk;
    const unsigned short* wp0 = Whh + (size_t)(0 * RNN + n0 + ns * 16 + lr) * RNN + kh * 256 + lk;
    const unsigned short* wp1 = Whh + (size_t)(1 * RNN + n0 + ns * 16 + lr) * RNN + kh * 256 + lk;
    const unsigned short* wp2 = Whh + (size_t)(2 * RNN + n0 + ns * 16 + lr) * RNN + kh * 256 + lk;
    const unsigned short* wp3 = Whh + (size_t)(3 * RNN + n0 + ns * 16 + lr) * RNN + kh * 256 + lk;
    #pragma unroll
    for (int kt = 0; kt < 8; ++kt) {
        bf16x8 a0 = *(const bf16x8*)(hw + kt * 32);
        bf16x8 a1 = *(const bf16x8*)(hw + 16 * RNN + kt * 32);
        bf16x8 b0 = *(const bf16x8*)(wp0 + kt * 32);
        bf16x8 b1 = *(const bf16x8*)(wp1 + kt * 32);
        bf16x8 b2 = *(const bf16x8*)(wp2 + kt * 32);
        bf16x8 b3 = *(const bf16x8*)(wp3 + kt * 32);
        acc[0][0] = __builtin_amdgcn_mfma_f32_16x16x32_bf16(a0, b0, acc[0][0], 0, 0, 0);
        acc[0][1] = __builtin_amdgcn_mfma_f32_16x16x32_bf16(a1, b0, acc[0][1], 0, 0, 0);
        acc[1][0] = __builtin_amdgcn_mfma_f32_16x16x32_bf16(a0, b1, acc[1][0], 0, 0, 0);
        acc[1][1] = __builtin_amdgcn_mfma_f32_16x16x32_bf16(a1, b1, acc[1][1], 0, 0, 0);
        acc[2][0] = __builtin_amdgcn_mfma_f32_16x16x32_bf16(a0, b2, acc[2][0], 0, 0, 0);
        acc[2][1] = __builtin_amdgcn_mfma_f32_16x16x32_bf16(a1, b2, acc[2][1], 0, 0, 0);
        acc[3][0] = __builtin_amdgcn_mfma_f32_16x16x32_bf16(a0, b3, acc[3][0], 0, 0, 0);
        acc[3][1] = __builtin_amdgcn_mfma_f32_16x16x32_bf16(a1, b3, acc[3][1], 0, 0, 0);
    }
    __syncthreads();                            // phase-0 stores visible

    // phase 2: reduce K quarters via LDS float atomics
    const int rbase = (lane >> 4) * 4;
    #pragma unroll
    for (int g = 0; g < 4; ++g)
        #pragma unroll
        for (int mi = 0; mi < 2; ++mi)
            #pragma unroll
            for (int r = 0; r < 4; ++r)
                atomicAdd(&gates[(g * 32 + mi * 16 + rbase + r) * 33 +
                                 ns * 16 + lr], acc[g][mi][r]);
    __syncthreads();

    // phase 3: LSTM elementwise; c in global f32; h -> global bf16
    #pragma unroll
    for (int q = 0; q < 2; ++q) {
        const int e = tid + q * 512;
        const int lm = e >> 5, ln = e & 31;
        const int b = m0 + lm, j = n0 + ln;
        const float xi = gates[(0 * 32 + lm) * 33 + ln];
        const float xf = gates[(1 * 32 + lm) * 33 + ln];
        const float xg_ = gates[(2 * 32 + lm) * 33 + ln];
        const float xo = gates[(3 * 32 + lm) * 33 + ln];
        const float si = 1.f / (1.f + expf(-xi));
        const float sf = 1.f / (1.f + expf(-xf));
        const float so = 1.f / (1.f + expf(-xo));
        const float cp = c[(size_t)b * RNN + j];
        const float cn = sf * cp + si * tanhf(xg_);
        const float hn = so * tanhf(cn);
        c[(size_t)b * RNN + j] = cn;
        h_next[(size_t)b * RNN + j] = f2bf(hn);
    }
}

// gate[b*50+t] = gatectx[b] + h_all[t+1][b]·w_gate[0:1024] ; one wave per row
__global__ void k_gate(const unsigned short* __restrict__ h,  // [12800][1024]
                       const float* __restrict__ wgate,
                       const float* __restrict__ gctx,
                       float* __restrict__ out1) {
    const int gw = (blockIdx.x * blockDim.x + threadIdx.x) >> 6;
    const int lane = threadIdx.x & 63;
    if (gw >= MROWS) return;
    const unsigned short* hr = h + (size_t)gw * RNN + lane * 16;
    const float* wr = wgate + lane * 16;
    float acc = 0.f;
    #pragma unroll
    for (int j = 0; j < 16; ++j) acc += bf2f(hr[j]) * wr[j];
    for (int off = 32; off; off >>= 1) acc += __shfl_down(acc, off);
    if (lane == 0) {
        const int t = gw >> 8, b = gw & 255;
        out1[b * TT + t] = acc + gctx[b];
    }
}

// ---------------- workspace layout (all offsets 1KB-aligned) ----------------
static const size_t OFF_WIH   = 0;                                    // 10.5 MB
static const size_t OFF_WHH   = OFF_WIH   + (size_t)G4 * INDIM * 2;   // 8 MB
static const size_t OFF_WPH   = OFF_WHH   + (size_t)G4 * RNN * 2;     // 2.6 MB
static const size_t OFF_FRM   = OFF_WPH   + (size_t)INDIM * RNN * 2;  // 32.8 MB
static const size_t OFF_XPROJ = OFF_FRM   + (size_t)MROWS * INDIM * 2;// 104.9 MB
static const size_t OFF_HALL  = OFF_XPROJ + (size_t)MROWS * G4 * 2;   // 26.7 MB
static const size_t OFF_C     = OFF_HALL  + (size_t)(TT + 1) * BB * RNN * 2;
static const size_t OFF_CTX   = OFF_C     + (size_t)BB * RNN * 4;
static const size_t OFF_GCTX  = OFF_CTX   + (size_t)BB * INDIM * 4;

extern "C" void kernel_launch(void* const* d_in, const int* in_sizes, int n_in,
                              void* d_out, int out_size, void* d_ws, size_t ws_size,
                              hipStream_t stream) {
    const float* context = (const float*)d_in[0];
    const float* target  = (const float*)d_in[1];
    const float* W_ih    = (const float*)d_in[2];
    const float* b_ih    = (const float*)d_in[3];
    const float* W_hh    = (const float*)d_in[4];
    const float* b_hh    = (const float*)d_in[5];
    const float* W_proj  = (const float*)d_in[6];
    const float* b_proj  = (const float*)d_in[7];
    const float* W_gate  = (const float*)d_in[8];
    const float* b_gate  = (const float*)d_in[9];
    float* out = (float*)d_out;
    char* ws = (char*)d_ws;

    unsigned short* wih_bf  = (unsigned short*)(ws + OFF_WIH);
    unsigned short* whh_bf  = (unsigned short*)(ws + OFF_WHH);
    unsigned short* wph_bf  = (unsigned short*)(ws + OFF_WPH);
    unsigned short* frames  = (unsigned short*)(ws + OFF_FRM);
    unsigned short* xproj   = (unsigned short*)(ws + OFF_XPROJ);
    unsigned short* h_all   = (unsigned short*)(ws + OFF_HALL);
    float*          c_buf   = (float*)(ws + OFF_C);
    float*          ctxproj = (float*)(ws + OFF_CTX);
    float*          gctx    = (float*)(ws + OFF_GCTX);

    // per-call init (harness does not re-zero ws between replays)
    hipMemsetAsync(h_all, 0, (size_t)BB * RNN * 2, stream);   // h0 slot
    hipMemsetAsync(c_buf, 0, (size_t)BB * RNN * 4, stream);   // c0

    k_f32_to_bf16<<<2048, 256, 0, stream>>>(W_ih, wih_bf, G4 * INDIM);
    k_f32_to_bf16<<<2048, 256, 0, stream>>>(W_hh, whh_bf, G4 * RNN);
    k_conv_wph<<<2048, 256, 0, stream>>>(W_proj, wph_bf);
    k_frames<<<2048, 256, 0, stream>>>(target, frames);
    k_ctxproj<<<(BB * INDIM + 255) / 256, 256, 0, stream>>>(context, W_proj,
                                                            b_proj, ctxproj);
    k_gatectx<<<1, 256, 0, stream>>>(context, W_gate, b_gate, gctx);

    k_gemm_xproj<<<dim3(G4 / 128, MROWS / 128), 256, 0, stream>>>(
        frames, wih_bf, b_ih, b_hh, xproj);

    for (int t = 0; t < TT; ++t) {
        k_step<<<dim3(32, 8), 512, 0, stream>>>(
            whh_bf, xproj + (size_t)t * BB * G4,
            h_all + (size_t)t * BB * RNN,
            h_all + (size_t)(t + 1) * BB * RNN, c_buf);
    }

    k_gemm_mel<<<dim3(INDIM / 128, MROWS / 128), 256, 0, stream>>>(
        h_all + (size_t)BB * RNN, wph_bf, ctxproj, out);
    k_gate<<<MROWS / 4, 256, 0, stream>>>(h_all + (size_t)BB * RNN, W_gate,
                                          gctx, out + (size_t)BB * NMEL * TMEL);
}

// Round 4
// 1127.047 us; speedup vs baseline: 4.6599x; 2.0527x over previous
//
#include <hip/hip_runtime.h>
#include <hip/hip_bf16.h>
#include <math.h>

// Problem constants
#define BB     256
#define NMEL   80
#define TMEL   800
#define NFR    16          // frames per step
#define TT     50          // decoder steps
#define RNN    1024
#define ENC    256
#define INDIM  1280        // RNN + ENC == MEL_DIM
#define G4     4096        // 4*RNN
#define MROWS  (TT*BB)     // 12800

typedef __attribute__((ext_vector_type(8))) short bf16x8;
typedef __attribute__((ext_vector_type(4))) float f32x4;

#define GAS __attribute__((address_space(1)))
#define LAS __attribute__((address_space(3)))

__device__ __forceinline__ unsigned short f2bf(float f) {
    unsigned int u = __float_as_uint(f);
    u += 0x7FFFu + ((u >> 16) & 1u);     // round-to-nearest-even
    return (unsigned short)(u >> 16);
}
__device__ __forceinline__ float bf2f(unsigned short s) {
    return __uint_as_float(((unsigned int)s) << 16);
}

// ---------------- prep kernels ----------------

__global__ void k_f32_to_bf16(const float* __restrict__ src,
                              unsigned short* __restrict__ dst, int n) {
    for (int i = blockIdx.x * blockDim.x + threadIdx.x; i < n;
         i += gridDim.x * blockDim.x)
        dst[i] = f2bf(src[i]);
}

// W_proj[:, 0:1024] -> bf16, N-permuted: dst row m' = mel*16+fr comes from
// W_proj row m = fr*80+mel. Makes mel-GEMM output contiguous along (t,fr).
__global__ void k_conv_wph(const float* __restrict__ wproj,
                           unsigned short* __restrict__ dst) {
    const int n = INDIM * RNN;
    for (int i = blockIdx.x * blockDim.x + threadIdx.x; i < n;
         i += gridDim.x * blockDim.x) {
        int mp = i >> 10, k = i & 1023;
        int mel = mp >> 4, fr = mp & 15;
        dst[i] = f2bf(wproj[(fr * NMEL + mel) * INDIM + k]);
    }
}

// teacher-forced inputs: frames[t][b][k] = (t==0)?0:target[b][k%80][t*16+k/80]
__global__ void k_frames(const float* __restrict__ target,
                         unsigned short* __restrict__ frames) {
    const int n = TT * BB * INDIM;
    for (int i = blockIdx.x * blockDim.x + threadIdx.x; i < n;
         i += gridDim.x * blockDim.x) {
        int k = i % INDIM;
        int rb = i / INDIM;
        int b = rb & (BB - 1);
        int t = rb >> 8;
        unsigned short v = 0;
        if (t > 0) {
            int mel = k % NMEL, fr = k / NMEL;
            v = f2bf(target[(b * NMEL + mel) * TMEL + t * NFR + fr]);
        }
        frames[i] = v;
    }
}

// ctxproj[b][m'] = b_proj[m] + context[b]·W_proj[m][1024:1280], m'=mel*16+fr,
// m = fr*80+mel (same permutation as k_conv_wph).
__global__ void k_ctxproj(const float* __restrict__ context,
                          const float* __restrict__ wproj,
                          const float* __restrict__ bproj,
                          float* __restrict__ ctx) {
    int i = blockIdx.x * blockDim.x + threadIdx.x;
    if (i >= BB * INDIM) return;
    int mp = i % INDIM, b = i / INDIM;
    int mel = mp >> 4, fr = mp & 15;
    int m = fr * NMEL + mel;
    const float* wr = wproj + (size_t)m * INDIM + RNN;
    const float* cb = context + b * ENC;
    float acc = bproj[m];
    for (int e = 0; e < ENC; ++e) acc += cb[e] * wr[e];
    ctx[(size_t)b * INDIM + mp] = acc;
}

// gatectx[b] = b_gate + context[b]·W_gate[0][1024:1280]
__global__ void k_gatectx(const float* __restrict__ context,
                          const float* __restrict__ wgate,
                          const float* __restrict__ bgate,
                          float* __restrict__ gctx) {
    int b = blockIdx.x * blockDim.x + threadIdx.x;
    if (b >= BB) return;
    float acc = bgate[0];
    const float* cb = context + b * ENC;
    for (int e = 0; e < ENC; ++e) acc += cb[e] * wgate[RNN + e];
    gctx[b] = acc;
}

// ---------------- m97-structure tile GEMM core ----------------
// 128x128 WG tile, BK=32, 4 waves of 64x64, global_load_lds(16B) staging,
// 2-barrier K loop. A [M][STRIDE], Bw [N][STRIDE] (row-major, C = A@Bw^T).
template<int STRIDE, int KDIM>
__device__ __forceinline__ void gemm_core(const unsigned short* __restrict__ A,
                                          const unsigned short* __restrict__ Bw,
                                          int mblk, int nblk,
                                          unsigned short* As, unsigned short* Bs,
                                          f32x4 acc[4][4]) {
    const int tid = threadIdx.x, lane = tid & 63, wid = tid >> 6;
    const int wm = (wid >> 1) * 64, wn = (wid & 1) * 64;
    const int lr = lane & 15, lko = (lane >> 4) * 8;
    // staging: chunk c covers LDS bytes [c*16, c*16+16); lane l of a call with
    // uniform base chunk cb gets chunk cb+l (HW adds lane*16 to LDS dest).
    const int c0 = wid * 128 + lane;          // call 0 chunk for this lane
    const int c1 = c0 + 64;                   // call 1
    const int r0 = c0 >> 2, o0 = (c0 & 3) * 8;
    const int r1 = c1 >> 2, o1 = (c1 & 3) * 8;
    const unsigned short* a0p = A + (size_t)(mblk + r0) * STRIDE + o0;
    const unsigned short* a1p = A + (size_t)(mblk + r1) * STRIDE + o1;
    const unsigned short* b0p = Bw + (size_t)(nblk + r0) * STRIDE + o0;
    const unsigned short* b1p = Bw + (size_t)(nblk + r1) * STRIDE + o1;
    unsigned short* da0 = As + wid * 1024;          // uniform per wave
    unsigned short* da1 = As + wid * 1024 + 512;
    unsigned short* db0 = Bs + wid * 1024;
    unsigned short* db1 = Bs + wid * 1024 + 512;
    for (int k0 = 0; k0 < KDIM; k0 += 32) {
        __syncthreads();   // previous compute done before LDS overwrite
        __builtin_amdgcn_global_load_lds((const GAS unsigned int*)(a0p + k0),
                                         (LAS unsigned int*)da0, 16, 0, 0);
        __builtin_amdgcn_global_load_lds((const GAS unsigned int*)(a1p + k0),
                                         (LAS unsigned int*)da1, 16, 0, 0);
        __builtin_amdgcn_global_load_lds((const GAS unsigned int*)(b0p + k0),
                                         (LAS unsigned int*)db0, 16, 0, 0);
        __builtin_amdgcn_global_load_lds((const GAS unsigned int*)(b1p + k0),
                                         (LAS unsigned int*)db1, 16, 0, 0);
        __syncthreads();   // compiler drains vmcnt before barrier
        bf16x8 af[4], bfv[4];
        #pragma unroll
        for (int mi = 0; mi < 4; ++mi)
            af[mi] = *(const bf16x8*)(As + (wm + mi * 16 + lr) * 32 + lko);
        #pragma unroll
        for (int ni = 0; ni < 4; ++ni)
            bfv[ni] = *(const bf16x8*)(Bs + (wn + ni * 16 + lr) * 32 + lko);
        #pragma unroll
        for (int mi = 0; mi < 4; ++mi)
            #pragma unroll
            for (int ni = 0; ni < 4; ++ni)
                acc[mi][ni] = __builtin_amdgcn_mfma_f32_16x16x32_bf16(
                    af[mi], bfv[ni], acc[mi][ni], 0, 0, 0);
    }
}

// GEMM 1: xproj = frames @ W_ih^T + b_ih + b_hh (bf16 out). M=12800 N=4096 K=1280
__global__ __launch_bounds__(256) void k_gemm_xproj(
    const unsigned short* __restrict__ A,   // [12800][1280]
    const unsigned short* __restrict__ Bw,  // [4096][1280]
    const float* __restrict__ b_ih, const float* __restrict__ b_hh,
    unsigned short* __restrict__ Cout)      // [12800][4096]
{
    __shared__ unsigned short As[4096], Bs[4096];
    f32x4 acc[4][4] = {};
    const int mblk = blockIdx.y * 128, nblk = blockIdx.x * 128;
    gemm_core<INDIM, INDIM>(A, Bw, mblk, nblk, As, Bs, acc);
    const int lane = threadIdx.x & 63, wid = threadIdx.x >> 6;
    const int wm = (wid >> 1) * 64, wn = (wid & 1) * 64, lr = lane & 15;
    #pragma unroll
    for (int ni = 0; ni < 4; ++ni) {
        const int col = nblk + wn + ni * 16 + lr;
        const float bias = b_ih[col] + b_hh[col];
        #pragma unroll
        for (int mi = 0; mi < 4; ++mi) {
            const int row0 = mblk + wm + mi * 16 + (lane >> 4) * 4;
            #pragma unroll
            for (int r = 0; r < 4; ++r)
                Cout[(size_t)(row0 + r) * G4 + col] = f2bf(acc[mi][ni][r] + bias);
        }
    }
}

// GEMM 2: mel = h_all[1:] @ Wp'^T + ctxproj', coalesced scatter via LDS
// transpose. M=12800, N=1280 (permuted col' = mel*16+fr), K=1024.
__global__ __launch_bounds__(256) void k_gemm_mel(
    const unsigned short* __restrict__ A,   // [12800][1024]
    const unsigned short* __restrict__ Bw,  // Wp' [1280][1024] (permuted)
    const float* __restrict__ ctxproj,      // [256][1280] (permuted)
    float* __restrict__ out0)               // [256][80][800]
{
    __shared__ unsigned short As[4096], Bs[4096];
    __shared__ float txp[4][16][20];        // per-wave transpose; 20: align+banks
    f32x4 acc[4][4] = {};
    const int mblk = blockIdx.y * 128, nblk = blockIdx.x * 128;
    gemm_core<RNN, RNN>(A, Bw, mblk, nblk, As, Bs, acc);
    const int lane = threadIdx.x & 63, wid = threadIdx.x >> 6;
    const int wm = (wid >> 1) * 64, wn = (wid & 1) * 64, lr = lane & 15;
    const int rbase = (lane >> 4) * 4;
    const int rowl = lane & 15, fq = lane >> 4;   // readback roles
    #pragma unroll
    for (int mi = 0; mi < 4; ++mi) {
        const int row0 = mblk + wm + mi * 16;     // 16 rows: same t, b0..b0+15
        const int t = row0 >> 8, b0 = row0 & 255;
        #pragma unroll
        for (int ni = 0; ni < 4; ++ni) {
            const int colbase = nblk + wn + ni * 16;  // one mel, fr 0..15
            const int mel = colbase >> 4;
            __syncthreads();                      // txp free for reuse
            #pragma unroll
            for (int r = 0; r < 4; ++r)
                txp[wid][rbase + r][lr] = acc[mi][ni][r];
            __syncthreads();                      // transpose visible
            const int bL = b0 + rowl;
            f32x4 v = *(const f32x4*)&txp[wid][rowl][fq * 4];
            f32x4 cx = *(const f32x4*)(ctxproj + (size_t)bL * INDIM +
                                       mel * 16 + fq * 4);
            *(f32x4*)(out0 + (size_t)(bL * NMEL + mel) * TMEL +
                      t * NFR + fq * 4) = v + cx;
        }
    }
}

// ---------------- per-step fused LSTM kernel (v3) ----------------
// gates = xproj[t] + h_prev @ Whh^T ; LSTM ; h_next(bf16), c(f32).
// Grid (64, 8): n0 = bx*16 (cols within RNN), m0 = by*32 (batch rows).
// 256 threads = 4 waves; wave w owns gate w's 32x16 tile, full K=1024.
// m97-style global_load_lds staging (async queue hides HBM/L2 latency —
// round-3's direct per-lane loads were latency-serialized at ~34us/step).
// 512 WGs -> 2 WG/CU (2 waves/SIMD) for cross-WG overlap of the drains.
__global__ __launch_bounds__(256) void k_step(
    const unsigned short* __restrict__ Whh,     // [4096][1024] bf16
    const unsigned short* __restrict__ xproj_t, // [256][4096] bf16
    const unsigned short* __restrict__ h_prev,  // [256][1024] bf16
    unsigned short* __restrict__ h_next,        // [256][1024] bf16
    float* __restrict__ c)                      // [256][1024] f32
{
    __shared__ unsigned short As[32 * 32];      // 2KB: h tile 32 rows x BK=32
    __shared__ unsigned short Bs[64 * 32];      // 4KB: Whh 64 vrows x BK=32
    __shared__ float gates[4][32][17];          // 8.7KB, +1 pad
    const int tid = threadIdx.x, lane = tid & 63, w = tid >> 6;
    const int n0 = blockIdx.x * 16, m0 = blockIdx.y * 32;
    const int lr = lane & 15, lk = (lane >> 4) * 8;

    // phase 0: gates := xproj tile. Wave-local: wave w fills gates[w][*][*].
    {
        const int row = (tid >> 1) & 31, ch = tid & 1;
        bf16x8 xv = *(const bf16x8*)(xproj_t + (size_t)(m0 + row) * G4 +
                                     w * RNN + n0 + ch * 8);
        #pragma unroll
        for (int j = 0; j < 8; ++j)
            gates[w][row][ch * 8 + j] = bf2f((unsigned short)xv[j]);
    }

    // staging addresses. B: chunk c = w*64+lane -> vrow vr = c>>2 (gate vr>>4,
    // col vr&15), 16B sub-chunk (c&3)*8. Wave w stages exactly gate w's rows.
    const int cB = w * 64 + lane;
    const int vrB = cB >> 2, coB = (cB & 3) * 8;
    const unsigned short* bsrc = Whh +
        (size_t)((vrB >> 4) * RNN + n0 + (vrB & 15)) * RNN + coB;
    unsigned short* bdst = Bs + w * 512;        // wave-uniform
    // A: 128 chunks staged by waves 2,3
    const int cA = (w - 2) * 64 + lane;
    const int rA = cA >> 2, coA = (cA & 3) * 8;
    const unsigned short* asrc = h_prev + (size_t)(m0 + rA) * RNN + coA;
    unsigned short* adst = As + (w - 2) * 512;  // wave-uniform

    f32x4 acc[2] = {};
    for (int k0 = 0; k0 < RNN; k0 += 32) {
        __syncthreads();   // previous compute done before LDS overwrite
        __builtin_amdgcn_global_load_lds((const GAS unsigned int*)(bsrc + k0),
                                         (LAS unsigned int*)bdst, 16, 0, 0);
        if (w >= 2)
            __builtin_amdgcn_global_load_lds((const GAS unsigned int*)(asrc + k0),
                                             (LAS unsigned int*)adst, 16, 0, 0);
        __syncthreads();   // drain
        bf16x8 a0 = *(const bf16x8*)(As + (lr) * 32 + lk);
        bf16x8 a1 = *(const bf16x8*)(As + (16 + lr) * 32 + lk);
        bf16x8 bv = *(const bf16x8*)(Bs + (w * 16 + lr) * 32 + lk);
        acc[0] = __builtin_amdgcn_mfma_f32_16x16x32_bf16(a0, bv, acc[0], 0, 0, 0);
        acc[1] = __builtin_amdgcn_mfma_f32_16x16x32_bf16(a1, bv, acc[1], 0, 0, 0);
    }
    // epilogue: add partials into gates[w] (wave-exclusive; phase-0 writes to
    // gates[w] were by this same wave -> intra-wave dep, no barrier needed)
    const int rbase = (lane >> 4) * 4;
    #pragma unroll
    for (int mi = 0; mi < 2; ++mi)
        #pragma unroll
        for (int r = 0; r < 4; ++r)
            gates[w][mi * 16 + rbase + r][lr] += acc[mi][r];
    __syncthreads();

    // phase 3: LSTM elementwise over 32x16 outputs; c f32 global
    #pragma unroll
    for (int q = 0; q < 2; ++q) {
        const int e = tid + q * 256;
        const int lm = e >> 4, ln = e & 15;
        const int b = m0 + lm, j = n0 + ln;
        const float xi = gates[0][lm][ln];
        const float xf = gates[1][lm][ln];
        const float xg = gates[2][lm][ln];
        const float xo = gates[3][lm][ln];
        const float si = 1.f / (1.f + expf(-xi));
        const float sf = 1.f / (1.f + expf(-xf));
        const float so = 1.f / (1.f + expf(-xo));
        const float cp = c[(size_t)b * RNN + j];
        const float cn = sf * cp + si * tanhf(xg);
        const float hn = so * tanhf(cn);
        c[(size_t)b * RNN + j] = cn;
        h_next[(size_t)b * RNN + j] = f2bf(hn);
    }
}

// gate[b*50+t] = gatectx[b] + h_all[t+1][b]·w_gate[0:1024] ; one wave per row
__global__ void k_gate(const unsigned short* __restrict__ h,  // [12800][1024]
                       const float* __restrict__ wgate,
                       const float* __restrict__ gctx,
                       float* __restrict__ out1) {
    const int gw = (blockIdx.x * blockDim.x + threadIdx.x) >> 6;
    const int lane = threadIdx.x & 63;
    if (gw >= MROWS) return;
    const unsigned short* hr = h + (size_t)gw * RNN + lane * 16;
    const float* wr = wgate + lane * 16;
    float acc = 0.f;
    #pragma unroll
    for (int j = 0; j < 16; ++j) acc += bf2f(hr[j]) * wr[j];
    for (int off = 32; off; off >>= 1) acc += __shfl_down(acc, off);
    if (lane == 0) {
        const int t = gw >> 8, b = gw & 255;
        out1[b * TT + t] = acc + gctx[b];
    }
}

// ---------------- workspace layout (all offsets 1KB-aligned) ----------------
static const size_t OFF_WIH   = 0;                                    // 10.5 MB
static const size_t OFF_WHH   = OFF_WIH   + (size_t)G4 * INDIM * 2;   // 8 MB
static const size_t OFF_WPH   = OFF_WHH   + (size_t)G4 * RNN * 2;     // 2.6 MB
static const size_t OFF_FRM   = OFF_WPH   + (size_t)INDIM * RNN * 2;  // 32.8 MB
static const size_t OFF_XPROJ = OFF_FRM   + (size_t)MROWS * INDIM * 2;// 104.9 MB
static const size_t OFF_HALL  = OFF_XPROJ + (size_t)MROWS * G4 * 2;   // 26.7 MB
static const size_t OFF_C     = OFF_HALL  + (size_t)(TT + 1) * BB * RNN * 2;
static const size_t OFF_CTX   = OFF_C     + (size_t)BB * RNN * 4;
static const size_t OFF_GCTX  = OFF_CTX   + (size_t)BB * INDIM * 4;

extern "C" void kernel_launch(void* const* d_in, const int* in_sizes, int n_in,
                              void* d_out, int out_size, void* d_ws, size_t ws_size,
                              hipStream_t stream) {
    const float* context = (const float*)d_in[0];
    const float* target  = (const float*)d_in[1];
    const float* W_ih    = (const float*)d_in[2];
    const float* b_ih    = (const float*)d_in[3];
    const float* W_hh    = (const float*)d_in[4];
    const float* b_hh    = (const float*)d_in[5];
    const float* W_proj  = (const float*)d_in[6];
    const float* b_proj  = (const float*)d_in[7];
    const float* W_gate  = (const float*)d_in[8];
    const float* b_gate  = (const float*)d_in[9];
    float* out = (float*)d_out;
    char* ws = (char*)d_ws;

    unsigned short* wih_bf  = (unsigned short*)(ws + OFF_WIH);
    unsigned short* whh_bf  = (unsigned short*)(ws + OFF_WHH);
    unsigned short* wph_bf  = (unsigned short*)(ws + OFF_WPH);
    unsigned short* frames  = (unsigned short*)(ws + OFF_FRM);
    unsigned short* xproj   = (unsigned short*)(ws + OFF_XPROJ);
    unsigned short* h_all   = (unsigned short*)(ws + OFF_HALL);
    float*          c_buf   = (float*)(ws + OFF_C);
    float*          ctxproj = (float*)(ws + OFF_CTX);
    float*          gctx    = (float*)(ws + OFF_GCTX);

    // per-call init (harness does not re-zero ws between replays)
    hipMemsetAsync(h_all, 0, (size_t)BB * RNN * 2, stream);   // h0 slot
    hipMemsetAsync(c_buf, 0, (size_t)BB * RNN * 4, stream);   // c0

    k_f32_to_bf16<<<2048, 256, 0, stream>>>(W_ih, wih_bf, G4 * INDIM);
    k_f32_to_bf16<<<2048, 256, 0, stream>>>(W_hh, whh_bf, G4 * RNN);
    k_conv_wph<<<2048, 256, 0, stream>>>(W_proj, wph_bf);
    k_frames<<<2048, 256, 0, stream>>>(target, frames);
    k_ctxproj<<<(BB * INDIM + 255) / 256, 256, 0, stream>>>(context, W_proj,
                                                            b_proj, ctxproj);
    k_gatectx<<<1, 256, 0, stream>>>(context, W_gate, b_gate, gctx);

    k_gemm_xproj<<<dim3(G4 / 128, MROWS / 128), 256, 0, stream>>>(
        frames, wih_bf, b_ih, b_hh, xproj);

    for (int t = 0; t < TT; ++t) {
        k_step<<<dim3(64, 8), 256, 0, stream>>>(
            whh_bf, xproj + (size_t)t * BB * G4,
            h_all + (size_t)t * BB * RNN,
            h_all + (size_t)(t + 1) * BB * RNN, c_buf);
    }

    k_gemm_mel<<<dim3(INDIM / 128, MROWS / 128), 256, 0, stream>>>(
        h_all + (size_t)BB * RNN, wph_bf, ctxproj, out);
    k_gate<<<MROWS / 4, 256, 0, stream>>>(h_all + (size_t)BB * RNN, W_gate,
                                          gctx, out + (size_t)BB * NMEL * TMEL);
}

// Round 5
// 1082.338 us; speedup vs baseline: 4.8524x; 1.0413x over previous
//
#include <hip/hip_runtime.h>
#include <hip/hip_bf16.h>
#include <math.h>

// Problem constants
#define BB     256
#define NMEL   80
#define TMEL   800
#define NFR    16          // frames per step
#define TT     50          // decoder steps
#define RNN    1024
#define ENC    256
#define INDIM  1280        // RNN + ENC == MEL_DIM
#define G4     4096        // 4*RNN
#define MROWS  (TT*BB)     // 12800

typedef __attribute__((ext_vector_type(8))) short bf16x8;
typedef __attribute__((ext_vector_type(4))) float f32x4;

#define GAS __attribute__((address_space(1)))
#define LAS __attribute__((address_space(3)))

__device__ __forceinline__ unsigned short f2bf(float f) {
    unsigned int u = __float_as_uint(f);
    u += 0x7FFFu + ((u >> 16) & 1u);     // round-to-nearest-even
    return (unsigned short)(u >> 16);
}
__device__ __forceinline__ float bf2f(unsigned short s) {
    return __uint_as_float(((unsigned int)s) << 16);
}

// ---------------- prep kernels ----------------

__global__ void k_f32_to_bf16(const float* __restrict__ src,
                              unsigned short* __restrict__ dst, int n) {
    for (int i = blockIdx.x * blockDim.x + threadIdx.x; i < n;
         i += gridDim.x * blockDim.x)
        dst[i] = f2bf(src[i]);
}

// W_proj[:, 0:1024] -> bf16, N-permuted: dst row m' = mel*16+fr comes from
// W_proj row m = fr*80+mel. Makes mel-GEMM output contiguous along (t,fr).
__global__ void k_conv_wph(const float* __restrict__ wproj,
                           unsigned short* __restrict__ dst) {
    const int n = INDIM * RNN;
    for (int i = blockIdx.x * blockDim.x + threadIdx.x; i < n;
         i += gridDim.x * blockDim.x) {
        int mp = i >> 10, k = i & 1023;
        int mel = mp >> 4, fr = mp & 15;
        dst[i] = f2bf(wproj[(fr * NMEL + mel) * INDIM + k]);
    }
}

// teacher-forced inputs: frames[t][b][k] = (t==0)?0:target[b][k%80][t*16+k/80]
__global__ void k_frames(const float* __restrict__ target,
                         unsigned short* __restrict__ frames) {
    const int n = TT * BB * INDIM;
    for (int i = blockIdx.x * blockDim.x + threadIdx.x; i < n;
         i += gridDim.x * blockDim.x) {
        int k = i % INDIM;
        int rb = i / INDIM;
        int b = rb & (BB - 1);
        int t = rb >> 8;
        unsigned short v = 0;
        if (t > 0) {
            int mel = k % NMEL, fr = k / NMEL;
            v = f2bf(target[(b * NMEL + mel) * TMEL + t * NFR + fr]);
        }
        frames[i] = v;
    }
}

// ctxproj[b][m'] = b_proj[m] + context[b]·W_proj[m][1024:1280], m'=mel*16+fr,
// m = fr*80+mel (same permutation as k_conv_wph).
__global__ void k_ctxproj(const float* __restrict__ context,
                          const float* __restrict__ wproj,
                          const float* __restrict__ bproj,
                          float* __restrict__ ctx) {
    int i = blockIdx.x * blockDim.x + threadIdx.x;
    if (i >= BB * INDIM) return;
    int mp = i % INDIM, b = i / INDIM;
    int mel = mp >> 4, fr = mp & 15;
    int m = fr * NMEL + mel;
    const float* wr = wproj + (size_t)m * INDIM + RNN;
    const float* cb = context + b * ENC;
    float acc = bproj[m];
    for (int e = 0; e < ENC; ++e) acc += cb[e] * wr[e];
    ctx[(size_t)b * INDIM + mp] = acc;
}

// gatectx[b] = b_gate + context[b]·W_gate[0][1024:1280]
__global__ void k_gatectx(const float* __restrict__ context,
                          const float* __restrict__ wgate,
                          const float* __restrict__ bgate,
                          float* __restrict__ gctx) {
    int b = blockIdx.x * blockDim.x + threadIdx.x;
    if (b >= BB) return;
    float acc = bgate[0];
    const float* cb = context + b * ENC;
    for (int e = 0; e < ENC; ++e) acc += cb[e] * wgate[RNN + e];
    gctx[b] = acc;
}

// ---------------- m97-structure tile GEMM core ----------------
// 128x128 WG tile, BK=32, 4 waves of 64x64, global_load_lds(16B) staging,
// 2-barrier K loop. A [M][STRIDE], Bw [N][STRIDE] (row-major, C = A@Bw^T).
template<int STRIDE, int KDIM>
__device__ __forceinline__ void gemm_core(const unsigned short* __restrict__ A,
                                          const unsigned short* __restrict__ Bw,
                                          int mblk, int nblk,
                                          unsigned short* As, unsigned short* Bs,
                                          f32x4 acc[4][4]) {
    const int tid = threadIdx.x, lane = tid & 63, wid = tid >> 6;
    const int wm = (wid >> 1) * 64, wn = (wid & 1) * 64;
    const int lr = lane & 15, lko = (lane >> 4) * 8;
    // staging: chunk c covers LDS bytes [c*16, c*16+16); lane l of a call with
    // uniform base chunk cb gets chunk cb+l (HW adds lane*16 to LDS dest).
    const int c0 = wid * 128 + lane;          // call 0 chunk for this lane
    const int c1 = c0 + 64;                   // call 1
    const int r0 = c0 >> 2, o0 = (c0 & 3) * 8;
    const int r1 = c1 >> 2, o1 = (c1 & 3) * 8;
    const unsigned short* a0p = A + (size_t)(mblk + r0) * STRIDE + o0;
    const unsigned short* a1p = A + (size_t)(mblk + r1) * STRIDE + o1;
    const unsigned short* b0p = Bw + (size_t)(nblk + r0) * STRIDE + o0;
    const unsigned short* b1p = Bw + (size_t)(nblk + r1) * STRIDE + o1;
    unsigned short* da0 = As + wid * 1024;          // uniform per wave
    unsigned short* da1 = As + wid * 1024 + 512;
    unsigned short* db0 = Bs + wid * 1024;
    unsigned short* db1 = Bs + wid * 1024 + 512;
    for (int k0 = 0; k0 < KDIM; k0 += 32) {
        __syncthreads();   // previous compute done before LDS overwrite
        __builtin_amdgcn_global_load_lds((const GAS unsigned int*)(a0p + k0),
                                         (LAS unsigned int*)da0, 16, 0, 0);
        __builtin_amdgcn_global_load_lds((const GAS unsigned int*)(a1p + k0),
                                         (LAS unsigned int*)da1, 16, 0, 0);
        __builtin_amdgcn_global_load_lds((const GAS unsigned int*)(b0p + k0),
                                         (LAS unsigned int*)db0, 16, 0, 0);
        __builtin_amdgcn_global_load_lds((const GAS unsigned int*)(b1p + k0),
                                         (LAS unsigned int*)db1, 16, 0, 0);
        __syncthreads();   // compiler drains vmcnt before barrier
        bf16x8 af[4], bfv[4];
        #pragma unroll
        for (int mi = 0; mi < 4; ++mi)
            af[mi] = *(const bf16x8*)(As + (wm + mi * 16 + lr) * 32 + lko);
        #pragma unroll
        for (int ni = 0; ni < 4; ++ni)
            bfv[ni] = *(const bf16x8*)(Bs + (wn + ni * 16 + lr) * 32 + lko);
        #pragma unroll
        for (int mi = 0; mi < 4; ++mi)
            #pragma unroll
            for (int ni = 0; ni < 4; ++ni)
                acc[mi][ni] = __builtin_amdgcn_mfma_f32_16x16x32_bf16(
                    af[mi], bfv[ni], acc[mi][ni], 0, 0, 0);
    }
}

// GEMM 1: xproj = frames @ W_ih^T + b_ih + b_hh (bf16 out). M=12800 N=4096 K=1280
__global__ __launch_bounds__(256) void k_gemm_xproj(
    const unsigned short* __restrict__ A,   // [12800][1280]
    const unsigned short* __restrict__ Bw,  // [4096][1280]
    const float* __restrict__ b_ih, const float* __restrict__ b_hh,
    unsigned short* __restrict__ Cout)      // [12800][4096]
{
    __shared__ unsigned short As[4096], Bs[4096];
    f32x4 acc[4][4] = {};
    const int mblk = blockIdx.y * 128, nblk = blockIdx.x * 128;
    gemm_core<INDIM, INDIM>(A, Bw, mblk, nblk, As, Bs, acc);
    const int lane = threadIdx.x & 63, wid = threadIdx.x >> 6;
    const int wm = (wid >> 1) * 64, wn = (wid & 1) * 64, lr = lane & 15;
    #pragma unroll
    for (int ni = 0; ni < 4; ++ni) {
        const int col = nblk + wn + ni * 16 + lr;
        const float bias = b_ih[col] + b_hh[col];
        #pragma unroll
        for (int mi = 0; mi < 4; ++mi) {
            const int row0 = mblk + wm + mi * 16 + (lane >> 4) * 4;
            #pragma unroll
            for (int r = 0; r < 4; ++r)
                Cout[(size_t)(row0 + r) * G4 + col] = f2bf(acc[mi][ni][r] + bias);
        }
    }
}

// GEMM 2: mel = h_all[1:] @ Wp'^T + ctxproj', coalesced scatter via LDS
// transpose. M=12800, N=1280 (permuted col' = mel*16+fr), K=1024.
__global__ __launch_bounds__(256) void k_gemm_mel(
    const unsigned short* __restrict__ A,   // [12800][1024]
    const unsigned short* __restrict__ Bw,  // Wp' [1280][1024] (permuted)
    const float* __restrict__ ctxproj,      // [256][1280] (permuted)
    float* __restrict__ out0)               // [256][80][800]
{
    __shared__ unsigned short As[4096], Bs[4096];
    __shared__ float txp[4][16][20];        // per-wave transpose; 20: align+banks
    f32x4 acc[4][4] = {};
    const int mblk = blockIdx.y * 128, nblk = blockIdx.x * 128;
    gemm_core<RNN, RNN>(A, Bw, mblk, nblk, As, Bs, acc);
    const int lane = threadIdx.x & 63, wid = threadIdx.x >> 6;
    const int wm = (wid >> 1) * 64, wn = (wid & 1) * 64, lr = lane & 15;
    const int rbase = (lane >> 4) * 4;
    const int rowl = lane & 15, fq = lane >> 4;   // readback roles
    #pragma unroll
    for (int mi = 0; mi < 4; ++mi) {
        const int row0 = mblk + wm + mi * 16;     // 16 rows: same t, b0..b0+15
        const int t = row0 >> 8, b0 = row0 & 255;
        #pragma unroll
        for (int ni = 0; ni < 4; ++ni) {
            const int colbase = nblk + wn + ni * 16;  // one mel, fr 0..15
            const int mel = colbase >> 4;
            __syncthreads();                      // txp free for reuse
            #pragma unroll
            for (int r = 0; r < 4; ++r)
                txp[wid][rbase + r][lr] = acc[mi][ni][r];
            __syncthreads();                      // transpose visible
            const int bL = b0 + rowl;
            f32x4 v = *(const f32x4*)&txp[wid][rowl][fq * 4];
            f32x4 cx = *(const f32x4*)(ctxproj + (size_t)bL * INDIM +
                                       mel * 16 + fq * 4);
            *(f32x4*)(out0 + (size_t)(bL * NMEL + mel) * TMEL +
                      t * NFR + fq * 4) = v + cx;
        }
    }
}

// ---------------- per-step fused LSTM kernel (v4) ----------------
// gates = xproj[t] + h_prev @ Whh^T ; LSTM ; h_next(bf16), c(f32).
// Grid (64, 4): n0 = bx*16 (cols within RNN), m0 = by*64 (batch rows).
// 512 threads = 8 waves: wave w -> gate g = w&3, m-half mh = w>>2.
// BK=64, double-buffered: STAGE(t+1) issued BEFORE compute(t); single
// __syncthreads (full vmcnt drain) per iter -> next tile's loads fly under
// current tile's ds_read+MFMA (T3 minimum 2-phase recipe).
// LDS XOR-swizzle (T2, both-sides rule #21): linear gload_lds dest,
// inverse-swizzled GLOBAL source (sub ^= row&7 per 16B chunk), swizzled
// ds_read -> 8 dwords/bank (optimal) instead of 8-way conflict.
__global__ __launch_bounds__(512) void k_step(
    const unsigned short* __restrict__ Whh,     // [4096][1024] bf16
    const unsigned short* __restrict__ xproj_t, // [256][4096] bf16
    const unsigned short* __restrict__ h_prev,  // [256][1024] bf16
    unsigned short* __restrict__ h_next,        // [256][1024] bf16
    float* __restrict__ c)                      // [256][1024] f32
{
    __shared__ unsigned short Asm[2][4096];     // 16KB: h tile 64 x 64 x dbuf
    __shared__ unsigned short Bsm[2][4096];     // 16KB: Whh 64 vrows x 64 x dbuf
    __shared__ float gates[4][64][17];          // 17.4KB, +1 pad
    const int tid = threadIdx.x, lane = tid & 63, w = tid >> 6;
    const int g = w & 3, mh = w >> 2;
    const int n0 = blockIdx.x * 16, m0 = blockIdx.y * 64;
    const int lr = lane & 15, q = lane >> 4;

    // staging chunk for this thread: c = w*64 + lane; row = c>>3, 16B-sub = c&7.
    // A vrow = batch row; B vrow vr: gate = vr>>4, col = n0 + (vr&15).
    const int cc = w * 64 + lane;
    const int rowc = cc >> 3, s2 = cc & 7;
    const unsigned short* asrc = h_prev + (size_t)(m0 + rowc) * RNN +
                                 ((s2 ^ (rowc & 7)) * 8);
    const unsigned short* bsrc = Whh +
        (size_t)((rowc >> 4) * RNN + n0 + (rowc & 15)) * RNN +
        ((s2 ^ (rowc & 7)) * 8);

#define STAGE_K(buf, k0) do {                                                  \
    __builtin_amdgcn_global_load_lds((const GAS unsigned int*)(asrc + (k0)),   \
        (LAS unsigned int*)&Asm[buf][w * 512], 16, 0, 0);                      \
    __builtin_amdgcn_global_load_lds((const GAS unsigned int*)(bsrc + (k0)),   \
        (LAS unsigned int*)&Bsm[buf][w * 512], 16, 0, 0); } while (0)

    STAGE_K(0, 0);
    // phase 0: gates := xproj tile (overlaps stage-0 flight)
    {
        const int gx = tid >> 7, row = (tid >> 1) & 63, ch = tid & 1;
        bf16x8 xv = *(const bf16x8*)(xproj_t + (size_t)(m0 + row) * G4 +
                                     gx * RNN + n0 + ch * 8);
        #pragma unroll
        for (int j = 0; j < 8; ++j)
            gates[gx][row][ch * 8 + j] = bf2f((unsigned short)xv[j]);
    }
    __syncthreads();                            // stage-0 drained

    f32x4 acc[2] = {};
    const int swz_a0 = (mh * 32 + lr) * 64;         // row base (shorts)
    const int swz_a1 = (mh * 32 + 16 + lr) * 64;
    const int swz_b  = (g * 16 + lr) * 64;
    const int sx = lr & 7;                          // row&7 swizzle term
    for (int t = 0; t < 16; ++t) {
        if (t < 15) STAGE_K((t + 1) & 1, (t + 1) * 64);
        const unsigned short* Ab = Asm[t & 1];
        const unsigned short* Bb = Bsm[t & 1];
        #pragma unroll
        for (int ks = 0; ks < 2; ++ks) {
            const int sub = ks * 4 + q;
            bf16x8 a0 = *(const bf16x8*)(Ab + swz_a0 + ((sub ^ sx) * 8));
            bf16x8 a1 = *(const bf16x8*)(Ab + swz_a1 + ((sub ^ sx) * 8));
            bf16x8 bv = *(const bf16x8*)(Bb + swz_b + ((sub ^ sx) * 8));
            acc[0] = __builtin_amdgcn_mfma_f32_16x16x32_bf16(a0, bv, acc[0], 0, 0, 0);
            acc[1] = __builtin_amdgcn_mfma_f32_16x16x32_bf16(a1, bv, acc[1], 0, 0, 0);
        }
        __syncthreads();   // drains vmcnt (next-tile stage) + lgkm; buffers swap
    }

    // epilogue: accumulate partials into gates (wave-exclusive region)
    const int rbase = q * 4;
    #pragma unroll
    for (int mi = 0; mi < 2; ++mi)
        #pragma unroll
        for (int r = 0; r < 4; ++r)
            gates[g][mh * 32 + mi * 16 + rbase + r][lr] += acc[mi][r];
    __syncthreads();

    // LSTM elementwise over 64x16 outputs; c f32 global
    #pragma unroll
    for (int q2 = 0; q2 < 2; ++q2) {
        const int e = tid + q2 * 512;
        const int lm = e >> 4, ln = e & 15;
        const int b = m0 + lm, j = n0 + ln;
        const float xi = gates[0][lm][ln];
        const float xf = gates[1][lm][ln];
        const float xg = gates[2][lm][ln];
        const float xo = gates[3][lm][ln];
        const float si = 1.f / (1.f + expf(-xi));
        const float sf = 1.f / (1.f + expf(-xf));
        const float so = 1.f / (1.f + expf(-xo));
        const float cp = c[(size_t)b * RNN + j];
        const float cn = sf * cp + si * tanhf(xg);
        const float hn = so * tanhf(cn);
        c[(size_t)b * RNN + j] = cn;
        h_next[(size_t)b * RNN + j] = f2bf(hn);
    }
#undef STAGE_K
}

// gate[b*50+t] = gatectx[b] + h_all[t+1][b]·w_gate[0:1024] ; one wave per row
__global__ void k_gate(const unsigned short* __restrict__ h,  // [12800][1024]
                       const float* __restrict__ wgate,
                       const float* __restrict__ gctx,
                       float* __restrict__ out1) {
    const int gw = (blockIdx.x * blockDim.x + threadIdx.x) >> 6;
    const int lane = threadIdx.x & 63;
    if (gw >= MROWS) return;
    const unsigned short* hr = h + (size_t)gw * RNN + lane * 16;
    const float* wr = wgate + lane * 16;
    float acc = 0.f;
    #pragma unroll
    for (int j = 0; j < 16; ++j) acc += bf2f(hr[j]) * wr[j];
    for (int off = 32; off; off >>= 1) acc += __shfl_down(acc, off);
    if (lane == 0) {
        const int t = gw >> 8, b = gw & 255;
        out1[b * TT + t] = acc + gctx[b];
    }
}

// ---------------- workspace layout (all offsets 1KB-aligned) ----------------
static const size_t OFF_WIH   = 0;                                    // 10.5 MB
static const size_t OFF_WHH   = OFF_WIH   + (size_t)G4 * INDIM * 2;   // 8 MB
static const size_t OFF_WPH   = OFF_WHH   + (size_t)G4 * RNN * 2;     // 2.6 MB
static const size_t OFF_FRM   = OFF_WPH   + (size_t)INDIM * RNN * 2;  // 32.8 MB
static const size_t OFF_XPROJ = OFF_FRM   + (size_t)MROWS * INDIM * 2;// 104.9 MB
static const size_t OFF_HALL  = OFF_XPROJ + (size_t)MROWS * G4 * 2;   // 26.7 MB
static const size_t OFF_C     = OFF_HALL  + (size_t)(TT + 1) * BB * RNN * 2;
static const size_t OFF_CTX   = OFF_C     + (size_t)BB * RNN * 4;
static const size_t OFF_GCTX  = OFF_CTX   + (size_t)BB * INDIM * 4;

extern "C" void kernel_launch(void* const* d_in, const int* in_sizes, int n_in,
                              void* d_out, int out_size, void* d_ws, size_t ws_size,
                              hipStream_t stream) {
    const float* context = (const float*)d_in[0];
    const float* target  = (const float*)d_in[1];
    const float* W_ih    = (const float*)d_in[2];
    const float* b_ih    = (const float*)d_in[3];
    const float* W_hh    = (const float*)d_in[4];
    const float* b_hh    = (const float*)d_in[5];
    const float* W_proj  = (const float*)d_in[6];
    const float* b_proj  = (const float*)d_in[7];
    const float* W_gate  = (const float*)d_in[8];
    const float* b_gate  = (const float*)d_in[9];
    float* out = (float*)d_out;
    char* ws = (char*)d_ws;

    unsigned short* wih_bf  = (unsigned short*)(ws + OFF_WIH);
    unsigned short* whh_bf  = (unsigned short*)(ws + OFF_WHH);
    unsigned short* wph_bf  = (unsigned short*)(ws + OFF_WPH);
    unsigned short* frames  = (unsigned short*)(ws + OFF_FRM);
    unsigned short* xproj   = (unsigned short*)(ws + OFF_XPROJ);
    unsigned short* h_all   = (unsigned short*)(ws + OFF_HALL);
    float*          c_buf   = (float*)(ws + OFF_C);
    float*          ctxproj = (float*)(ws + OFF_CTX);
    float*          gctx    = (float*)(ws + OFF_GCTX);

    // per-call init (harness does not re-zero ws between replays)
    hipMemsetAsync(h_all, 0, (size_t)BB * RNN * 2, stream);   // h0 slot
    hipMemsetAsync(c_buf, 0, (size_t)BB * RNN * 4, stream);   // c0

    k_f32_to_bf16<<<2048, 256, 0, stream>>>(W_ih, wih_bf, G4 * INDIM);
    k_f32_to_bf16<<<2048, 256, 0, stream>>>(W_hh, whh_bf, G4 * RNN);
    k_conv_wph<<<2048, 256, 0, stream>>>(W_proj, wph_bf);
    k_frames<<<2048, 256, 0, stream>>>(target, frames);
    k_ctxproj<<<(BB * INDIM + 255) / 256, 256, 0, stream>>>(context, W_proj,
                                                            b_proj, ctxproj);
    k_gatectx<<<1, 256, 0, stream>>>(context, W_gate, b_gate, gctx);

    k_gemm_xproj<<<dim3(G4 / 128, MROWS / 128), 256, 0, stream>>>(
        frames, wih_bf, b_ih, b_hh, xproj);

    for (int t = 0; t < TT; ++t) {
        k_step<<<dim3(64, 4), 512, 0, stream>>>(
            whh_bf, xproj + (size_t)t * BB * G4,
            h_all + (size_t)t * BB * RNN,
            h_all + (size_t)(t + 1) * BB * RNN, c_buf);
    }

    k_gemm_mel<<<dim3(INDIM / 128, MROWS / 128), 256, 0, stream>>>(
        h_all + (size_t)BB * RNN, wph_bf, ctxproj, out);
    k_gate<<<MROWS / 4, 256, 0, stream>>>(h_all + (size_t)BB * RNN, W_gate,
                                          gctx, out + (size_t)BB * NMEL * TMEL);
}